// Round 9
// baseline (238.684 us; speedup 1.0000x reference)
//
#include <hip/hip_runtime.h>
#include <hip/hip_bf16.h>

#define NB 32
#define NN 8400
#define NC 80
#define KPRE 512
#define MAXOUT 100
#define NGRP 263   // blocks per image; each block = 2 waves x 16 rows = 32 rows (525 groups of 16)

// ---------------- Kernel A: scores + per-anchor decode + per-block max ----------------
// Each wave stages 16 rows (340 float4 = 5.4 KB); block LDS 10.9 KB -> 14 blocks/CU.
// 4 lanes share a row: q=lane&3 scans classes 20q..20q+19; two shfl_xor steps combine.
__global__ __launch_bounds__(128) void score_kernel(const float* __restrict__ pred,
                                                    float* __restrict__ scores,
                                                    unsigned* __restrict__ wmaxg,
                                                    float4* __restrict__ rawbox,
                                                    float4* __restrict__ minfo) {
    int b = blockIdx.y;
    int w = threadIdx.x >> 6, lane = threadIdx.x & 63;
    int g = blockIdx.x * 2 + w;                    // 16-row group in image (0..524 valid)
    __shared__ float4 stg4[2][340];                // 16 rows x 85 floats per wave
    const float4* p4 = (const float4*)pred;
    size_t base4 = (size_t)b * 178500 + (size_t)g * 340;
    size_t img_end4 = ((size_t)b + 1) * 178500;
    for (int k = lane; k < 340; k += 64) {
        size_t e = base4 + k;
        if (e >= img_end4) e = img_end4 - 1;       // clamp tail (invalid groups discarded below)
        stg4[w][k] = p4[e];
    }
    // no cross-wave LDS sharing -> no barrier needed here (compiler waits lgkmcnt)
    int rl = lane >> 2, q = lane & 3;
    int row = g * 16 + rl;
    const float* r = (const float*)&stg4[w][0] + rl * 85;
    float cx = r[0], cy = r[1], bw = r[2], bh = r[3], obj = r[4];
    int c0 = 5 + q * 20;
    float cc = r[c0];
    int cp = q * 20;
    for (int c = 1; c < 20; c++) {
        float v = r[c0 + c];
        if (v > cc) { cc = v; cp = q * 20 + c; }   // strict >: first-max within quarter
    }
    // combine 4-lane group; tie -> lower class index
    {
        float cc1 = __shfl_xor(cc, 1, 64); int cp1 = __shfl_xor(cp, 1, 64);
        bool take = (cc1 > cc) || (cc1 == cc && cp1 < cp);
        cc = take ? cc1 : cc; cp = take ? cp1 : cp;
        float cc2 = __shfl_xor(cc, 2, 64); int cp2 = __shfl_xor(cp, 2, 64);
        take = (cc2 > cc) || (cc2 == cc && cp2 < cp);
        cc = take ? cc2 : cc; cp = take ? cp2 : cp;
    }
    float s = __fmul_rn(obj, cc);
    float hw = __fmul_rn(bw, 0.5f), hh = __fmul_rn(bh, 0.5f);
    float x1 = cx - hw, y1 = cy - hh, x2 = cx + hw, y2 = cy + hh;
    // redistribute: lane l<16 takes row l's result (lives in lane 4l), coalesced writes
    int srcl = (lane & 15) * 4;
    float v0 = __shfl(x1, srcl, 64);
    float v1 = __shfl(y1, srcl, 64);
    float v2 = __shfl(x2, srcl, 64);
    float v3 = __shfl(y2, srcl, 64);
    float v4 = __shfl(obj, srcl, 64);
    float v5 = __shfl(cc, srcl, 64);
    int   v6 = __shfl(cp, srcl, 64);
    float v7 = __shfl(s, srcl, 64);
    int wrow = g * 16 + (lane & 15);
    if (lane < 16 && wrow < NN) {
        size_t idx = (size_t)b * NN + wrow;
        scores[idx] = v7;
        rawbox[idx] = make_float4(v0, v1, v2, v3);
        minfo[idx]  = make_float4(v4, v5, (float)v6, v7);
    }
    // block max (invalid rows -> 0)
    if (row >= NN) s = 0.0f;
    unsigned bits = __float_as_uint(s);
    for (int o = 32; o > 0; o >>= 1) {
        unsigned other = (unsigned)__shfl_down((int)bits, o, 64);
        if (other > bits) bits = other;
    }
    __shared__ unsigned wmax[2];
    if (lane == 0) wmax[w] = bits;
    __syncthreads();
    if (threadIdx.x == 0) {
        unsigned m = wmax[0] > wmax[1] ? wmax[0] : wmax[1];
        wmaxg[b * NGRP + blockIdx.x] = m;          // every slot written -> no init needed
    }
}

// ---- wave-0 helper: largest bin B with suffix(B) >= T over hist[0..nb); R = T - suffix(B+1)
__device__ __forceinline__ void find_bin(const unsigned* hist, int nb, unsigned T, int lane,
                                         int* outB, unsigned* outR) {
    unsigned running = 0;
    for (int c = nb / 64 - 1; c >= 0; c--) {
        unsigned v = hist[c * 64 + lane];
        unsigned s = v;
        for (int off = 1; off < 64; off <<= 1) {
            unsigned u = (unsigned)__shfl_down((int)s, off, 64);
            if (lane + off < 64) s += u;
        }
        unsigned total0 = (unsigned)__shfl((int)s, 0, 64);
        if (total0 + running >= T) {
            unsigned long long mask = __ballot(s + running >= T);
            int m = 63 - __clzll(mask);
            unsigned sm = (unsigned)__shfl((int)s, m, 64);
            unsigned vm = (unsigned)__shfl((int)v, m, 64);
            if (lane == 0) { *outB = c * 64 + m; *outR = T - (sm + running - vm); }
            return;
        }
        running += total0;
    }
    if (lane == 0) { *outB = 0; *outR = T; }
}

// ---------------- Kernel B (fused): radix select + IoU bitmatrix + greedy scan + output ----------------
// One block per image, 1024 threads. skey LDS region is reused as the 528x8-word IoU matrix
// after compaction (last skey reader) completes.
__global__ __launch_bounds__(1024) void nms_fused_kernel(const float* __restrict__ scores,
                                                         const unsigned* __restrict__ wmaxg,
                                                         const float4* __restrict__ rawbox,
                                                         const float4* __restrict__ minfo,
                                                         float* __restrict__ out) {
    int b = blockIdx.x, t = threadIdx.x;
    __shared__ alignas(16) unsigned char region[33792];   // skey (NN u32 = 33600 B) / mat (528*8 u64 = 33792 B)
    unsigned* skey = (unsigned*)region;
    unsigned long long* mat = (unsigned long long*)region;
    __shared__ unsigned hist[2048];               // 8 KB
    __shared__ float4 sbox[KPRE];                 // 8 KB (class-offset boxes)
    __shared__ unsigned long long list[KPRE];     // 4 KB
    __shared__ unsigned long long sorted[KPRE];   // 4 KB
    __shared__ int elist[256];                    // 1 KB
    __shared__ unsigned long long skeep[8];
    __shared__ int S_B[3];
    __shared__ unsigned S_T[3];
    __shared__ int S_cnt, S_ecnt;
    __shared__ float S_conf;

    if (t == 0) { S_cnt = 0; S_ecnt = 0; }
    // conf = min(0.25, max score) from per-block maxima
    if (t < 64) {
        unsigned m = 0;
        for (int i = t; i < NGRP; i += 64) {
            unsigned v = wmaxg[b * NGRP + i];
            if (v > m) m = v;
        }
        for (int off = 32; off > 0; off >>= 1) {
            unsigned o = (unsigned)__shfl_down((int)m, off, 64);
            if (o > m) m = o;
        }
        if (t == 0) S_conf = fminf(0.25f, __uint_as_float(m));
    }
    for (int i = t; i < 2048; i += 1024) hist[i] = 0;
    __syncthreads();
    float conf = S_conf;
    const float4* sc4 = (const float4*)(scores + (size_t)b * NN);
    for (int n = t; n < NN / 4; n += 1024) {
        float4 v = sc4[n];
        skey[n * 4 + 0] = (v.x >= conf) ? __float_as_uint(v.x) : 0u;
        skey[n * 4 + 1] = (v.y >= conf) ? __float_as_uint(v.y) : 0u;
        skey[n * 4 + 2] = (v.z >= conf) ? __float_as_uint(v.z) : 0u;
        skey[n * 4 + 3] = (v.w >= conf) ? __float_as_uint(v.w) : 0u;
    }
    __syncthreads();
    // pass A: bits[31:21]
    for (int n = t; n < NN; n += 1024) atomicAdd(&hist[skey[n] >> 21], 1u);
    __syncthreads();
    if (t < 64) find_bin(hist, 2048, 512u, t, &S_B[0], &S_T[0]);
    __syncthreads();
    int B1 = S_B[0]; unsigned R1 = S_T[0];
    for (int i = t; i < 2048; i += 1024) hist[i] = 0;
    __syncthreads();
    // pass B: bits[20:10] within top11==B1
    for (int n = t; n < NN; n += 1024) {
        unsigned k = skey[n];
        if ((int)(k >> 21) == B1) atomicAdd(&hist[(k >> 10) & 0x7FFu], 1u);
    }
    __syncthreads();
    if (t < 64) find_bin(hist, 2048, R1, t, &S_B[1], &S_T[1]);
    __syncthreads();
    unsigned P = ((unsigned)B1 << 11) | (unsigned)S_B[1];
    unsigned R2 = S_T[1];
    if (t < 1024) hist[t] = 0;
    __syncthreads();
    // pass C: bits[9:0] within top22==P
    for (int n = t; n < NN; n += 1024) {
        unsigned k = skey[n];
        if ((k >> 10) == P) atomicAdd(&hist[k & 0x3FFu], 1u);
    }
    __syncthreads();
    if (t < 64) find_bin(hist, 1024, R2, t, &S_B[2], &S_T[2]);
    __syncthreads();
    unsigned K32 = (P << 10) | (unsigned)S_B[2];
    unsigned R3 = S_T[2];
    // compact winners (unordered) + boundary ties — LAST reader of skey
    for (int n = t; n < NN; n += 1024) {
        unsigned k = skey[n];
        if (k > K32) {
            int pos = atomicAdd(&S_cnt, 1);
            list[pos] = ((unsigned long long)k << 32) | (unsigned long long)(unsigned)(~(unsigned)n);
        }
        if (K32 != 0u && k == K32) {
            int ep = atomicAdd(&S_ecnt, 1);
            if (ep < 256) elist[ep] = n;
        }
    }
    __syncthreads();
    int ecnt = S_ecnt; if (ecnt > 256) ecnt = 256;
    if (t < ecnt) {
        int my = elist[t];
        int r = 0;
        for (int j = 0; j < ecnt; j++) r += (elist[j] < my) ? 1 : 0;
        if ((unsigned)r < R3) {
            int pos = atomicAdd(&S_cnt, 1);
            list[pos] = ((unsigned long long)K32 << 32) | (unsigned long long)(unsigned)(~(unsigned)my);
        }
    }
    __syncthreads();
    int nval = S_cnt;                              // == 512 unless fewer valid
    for (int i = nval + t; i < KPRE; i += 1024) list[i] = 0ull;
    __syncthreads();
    // exact rank via all-pairs compare -> sorted (descending top_k order)
    if (t < KPRE) {
        unsigned long long K0 = list[t];
        int r0 = 0;
        for (int j = 0; j < KPRE; j++) {
            unsigned long long L = list[j];        // wave-uniform broadcast read
            r0 += (L > K0) ? 1 : 0;
        }
        if (K0 != 0ull) sorted[r0] = K0; else sorted[t] = 0ull;
    }
    __syncthreads();
    // gather class-offset boxes into LDS (invalid rows -> garbage, never kept/never in keepW)
    if (t < KPRE) {
        unsigned long long key = sorted[t];
        unsigned n = ~(unsigned)key;
        if (((unsigned)(key >> 32)) == 0u) n = 0;
        size_t src = (size_t)b * NN + n;
        float4 rb = rawbox[src];
        float cpf = minfo[src].z;
        float off = __fmul_rn(cpf, 4096.0f);
        sbox[t] = make_float4(rb.x + off, rb.y + off, rb.z + off, rb.w + off);
    }
    __syncthreads();
    // IoU bitmatrix into mat (overwrites skey region — all skey reads completed above)
    {
        int r = t >> 1, h = t & 1;
        float4 bi = sbox[r];
        float ai = __fmul_rn(bi.z - bi.x, bi.w - bi.y);
        int base = h << 8;
#pragma unroll
        for (int wd = 0; wd < 4; wd++) {
            unsigned long long bits = 0ull;
            int j0 = base + wd * 64;
            int lim = r - j0; if (lim > 64) lim = 64;
            for (int s_ = 0; s_ < lim; s_++) {
                float4 bj = sbox[j0 + s_];         // wave-broadcast read (conflict-free)
                float xx1 = fmaxf(bi.x, bj.x);
                float yy1 = fmaxf(bi.y, bj.y);
                float xx2 = fminf(bi.z, bj.z);
                float yy2 = fminf(bi.w, bj.w);
                float iw = fmaxf(xx2 - xx1, 0.0f);
                float ih = fmaxf(yy2 - yy1, 0.0f);
                float inter = __fmul_rn(iw, ih);
                float aj = __fmul_rn(bj.z - bj.x, bj.w - bj.y);
                float uni = (ai + aj) - inter;
                float iou = inter / (uni + 1e-9f);
                if (iou > 0.45f) bits |= (1ull << s_);
            }
            mat[(size_t)r * 8 + h * 4 + wd] = bits;
        }
        if (t < 128) mat[4096 + t] = 0ull;         // zero 16 pad rows for scan prefetch
    }
    __syncthreads();
    // sequential greedy scan, wave 0 only; 8-deep ping-pong register prefetch
    if (t < 64) {
        int w8 = t & 7;
        unsigned long long keepW = 0ull;
#define STEP(ii, rwreg) { \
        bool hit = ((rwreg) & keepW) != 0ull; \
        unsigned long long bal = __ballot(hit); \
        bool kept = (bal == 0ull) && ((ii) < nval); \
        unsigned long long sb_ = (kept && (t == ((ii) >> 6))) ? (1ull << ((ii) & 63)) : 0ull; \
        keepW |= sb_; }
        unsigned long long A[8], Bf[8];
#pragma unroll
        for (int k = 0; k < 8; k++) A[k] = mat[(size_t)(0 + k) * 8 + w8];
#pragma unroll
        for (int k = 0; k < 8; k++) Bf[k] = mat[(size_t)(8 + k) * 8 + w8];
        for (int g = 0; g < 64; g += 2) {
            int base = g * 8;
#pragma unroll
            for (int k = 0; k < 8; k++) { STEP(base + k, A[k]); }
#pragma unroll
            for (int k = 0; k < 8; k++) A[k] = mat[(size_t)(base + 16 + k) * 8 + w8];
#pragma unroll
            for (int k = 0; k < 8; k++) { STEP(base + 8 + k, Bf[k]); }
#pragma unroll
            for (int k = 0; k < 8; k++) Bf[k] = mat[(size_t)(base + 24 + k) * 8 + w8];
        }
#undef STEP
        if (t < 8) skeep[t] = keepW;
    }
    __syncthreads();
    // output: kept rows ranked by position; rows >= nkept zeroed
    float* dets = out + (size_t)b * (MAXOUT * 7);
    float* mask = out + (size_t)NB * MAXOUT * 7 + (size_t)b * MAXOUT;
    int nkept = 0;
#pragma unroll
    for (int k = 0; k < 8; k++) nkept += __popcll(skeep[k]);
    if (t < MAXOUT && t >= nkept) {
        float* row = dets + t * 7;
        row[0] = 0.0f; row[1] = 0.0f; row[2] = 0.0f; row[3] = 0.0f;
        row[4] = 0.0f; row[5] = 0.0f; row[6] = 0.0f;
        mask[t] = 0.0f;
    }
    if (t < KPRE) {
        int wq = t >> 6;
        unsigned long long kw = skeep[wq];
        if ((kw >> (t & 63)) & 1ull) {
            int rank = 0;
            for (int w2 = 0; w2 < wq; w2++) rank += __popcll(skeep[w2]);
            rank += __popcll(kw & ((1ull << (t & 63)) - 1ull));
            if (rank < MAXOUT) {
                unsigned n = ~(unsigned)sorted[t];
                size_t src = (size_t)b * NN + n;
                float4 rb = rawbox[src];
                float4 mi = minfo[src];
                float* row = dets + rank * 7;
                row[0] = rb.x; row[1] = rb.y; row[2] = rb.z; row[3] = rb.w;
                row[4] = mi.x; row[5] = mi.y; row[6] = mi.z;
                mask[rank] = 1.0f;
            }
        }
    }
}

extern "C" void kernel_launch(void* const* d_in, const int* in_sizes, int n_in,
                              void* d_out, int out_size, void* d_ws, size_t ws_size,
                              hipStream_t stream) {
    const float* pred = (const float*)d_in[0];
    float* out = (float*)d_out;

    char* ws = (char*)d_ws;
    unsigned* wmaxg = (unsigned*)ws;                                   // 32*263*4 = 33,664 -> pad 33,792
    float* scores = (float*)(ws + 33792);                              // 1,075,200 -> 1,108,992
    float4* rawbox = (float4*)(ws + 1108992);                          // 4,300,800 -> 5,409,792
    float4* minfo  = (float4*)(ws + 5409792);                          // 4,300,800 -> 9,710,592

    dim3 gA((525 + 1) / 2, NB);   // 263 blocks/image
    score_kernel<<<gA, 128, 0, stream>>>(pred, scores, wmaxg, rawbox, minfo);
    nms_fused_kernel<<<NB, 1024, 0, stream>>>(scores, wmaxg, rawbox, minfo, out);
}

// Round 10
// 203.362 us; speedup vs baseline: 1.1737x; 1.1737x over previous
//
#include <hip/hip_runtime.h>
#include <hip/hip_bf16.h>

#define NB 32
#define NN 8400
#define NC 80
#define KPRE 512
#define MAXOUT 100
#define NGRP 263   // blocks per image; each block = 2 waves x 16 rows

// ---------------- Kernel A: scores + per-anchor decode + per-block max ----------------
// Each wave stages 16 rows (340 float4 = 5.4 KB); block LDS 10.9 KB -> 14 blocks/CU.
// 4 lanes share a row: q=lane&3 scans classes 20q..20q+19; two shfl_xor steps combine.
__global__ __launch_bounds__(128) void score_kernel(const float* __restrict__ pred,
                                                    float* __restrict__ scores,
                                                    unsigned* __restrict__ wmaxg,
                                                    float4* __restrict__ rawbox,
                                                    float4* __restrict__ minfo) {
    int b = blockIdx.y;
    int w = threadIdx.x >> 6, lane = threadIdx.x & 63;
    int g = blockIdx.x * 2 + w;                    // 16-row group in image (0..524 valid)
    __shared__ float4 stg4[2][340];                // 16 rows x 85 floats per wave
    const float4* p4 = (const float4*)pred;
    size_t base4 = (size_t)b * 178500 + (size_t)g * 340;
    size_t img_end4 = ((size_t)b + 1) * 178500;
    for (int k = lane; k < 340; k += 64) {
        size_t e = base4 + k;
        if (e >= img_end4) e = img_end4 - 1;       // clamp tail (invalid groups discarded below)
        stg4[w][k] = p4[e];
    }
    // no cross-wave LDS sharing -> no barrier needed (compiler waits lgkmcnt within wave)
    int rl = lane >> 2, q = lane & 3;
    int row = g * 16 + rl;
    const float* r = (const float*)&stg4[w][0] + rl * 85;
    float cx = r[0], cy = r[1], bw = r[2], bh = r[3], obj = r[4];
    int c0 = 5 + q * 20;
    float cc = r[c0];
    int cp = q * 20;
    for (int c = 1; c < 20; c++) {
        float v = r[c0 + c];
        if (v > cc) { cc = v; cp = q * 20 + c; }   // strict >: first-max within quarter
    }
    // combine 4-lane group; tie -> lower class index
    {
        float cc1 = __shfl_xor(cc, 1, 64); int cp1 = __shfl_xor(cp, 1, 64);
        bool take = (cc1 > cc) || (cc1 == cc && cp1 < cp);
        cc = take ? cc1 : cc; cp = take ? cp1 : cp;
        float cc2 = __shfl_xor(cc, 2, 64); int cp2 = __shfl_xor(cp, 2, 64);
        take = (cc2 > cc) || (cc2 == cc && cp2 < cp);
        cc = take ? cc2 : cc; cp = take ? cp2 : cp;
    }
    float s = __fmul_rn(obj, cc);
    float hw = __fmul_rn(bw, 0.5f), hh = __fmul_rn(bh, 0.5f);
    float x1 = cx - hw, y1 = cy - hh, x2 = cx + hw, y2 = cy + hh;
    // redistribute: lane l<16 takes row l's result (lives in lane 4l), coalesced writes
    int srcl = (lane & 15) * 4;
    float v0 = __shfl(x1, srcl, 64);
    float v1 = __shfl(y1, srcl, 64);
    float v2 = __shfl(x2, srcl, 64);
    float v3 = __shfl(y2, srcl, 64);
    float v4 = __shfl(obj, srcl, 64);
    float v5 = __shfl(cc, srcl, 64);
    int   v6 = __shfl(cp, srcl, 64);
    float v7 = __shfl(s, srcl, 64);
    int wrow = g * 16 + (lane & 15);
    if (lane < 16 && wrow < NN) {
        size_t idx = (size_t)b * NN + wrow;
        scores[idx] = v7;
        rawbox[idx] = make_float4(v0, v1, v2, v3);
        minfo[idx]  = make_float4(v4, v5, (float)v6, v7);
    }
    // block max (invalid rows -> 0)
    if (row >= NN) s = 0.0f;
    unsigned bits = __float_as_uint(s);
    for (int o = 32; o > 0; o >>= 1) {
        unsigned other = (unsigned)__shfl_down((int)bits, o, 64);
        if (other > bits) bits = other;
    }
    __shared__ unsigned wmax[2];
    if (lane == 0) wmax[w] = bits;
    __syncthreads();
    if (threadIdx.x == 0) {
        unsigned m = wmax[0] > wmax[1] ? wmax[0] : wmax[1];
        wmaxg[b * NGRP + blockIdx.x] = m;          // every slot written -> no init needed
    }
}

// ---- wave-0 helper: largest bin B with suffix(B) >= T over hist[0..(cstart+1)*64);
// R = T - suffix(B+1). Scans chunks downward starting at cstart.
__device__ __forceinline__ void find_bin(const unsigned* hist, int cstart, unsigned T, int lane,
                                         int* outB, unsigned* outR) {
    unsigned running = 0;
    for (int c = cstart; c >= 0; c--) {
        unsigned v = hist[c * 64 + lane];
        unsigned s = v;
        for (int off = 1; off < 64; off <<= 1) {
            unsigned u = (unsigned)__shfl_down((int)s, off, 64);
            if (lane + off < 64) s += u;
        }
        unsigned total0 = (unsigned)__shfl((int)s, 0, 64);
        if (total0 + running >= T) {
            unsigned long long mask = __ballot(s + running >= T);
            int m = 63 - __clzll(mask);
            unsigned sm = (unsigned)__shfl((int)s, m, 64);
            unsigned vm = (unsigned)__shfl((int)v, m, 64);
            if (lane == 0) { *outB = c * 64 + m; *outR = T - (sm + running - vm); }
            return;
        }
        running += total0;
    }
    if (lane == 0) { *outB = 0; *outR = T; }   // fewer than T valid keys in range
}

// ---------------- Kernel B: top-512 radix select (2 passes + exact boundary) + tiny gather ----
// key = conf-zeroed score bits. Pass A: bits[31:21]; pass B: bits[20:10]; boundary bin at 22
// bits resolved exactly by all-pairs rank over full (key,~idx) (expected ~1 entry).
__global__ __launch_bounds__(1024) void select_kernel(const float* __restrict__ scores,
                                                      const unsigned* __restrict__ wmaxg,
                                                      const float4* __restrict__ rawbox,
                                                      const float4* __restrict__ minfo,
                                                      int* __restrict__ nvalid,
                                                      float4* __restrict__ boxoff,
                                                      float4* __restrict__ boxraw,
                                                      float4* __restrict__ meta) {
    int b = blockIdx.x, t = threadIdx.x;
    __shared__ unsigned skey[NN];                 // 33.6 KB
    __shared__ unsigned histA[2048];              // 8 KB
    __shared__ unsigned histB[2048];              // 8 KB
    __shared__ unsigned long long list[KPRE];     // 4 KB
    __shared__ unsigned long long sorted[KPRE];   // 4 KB
    __shared__ unsigned long long elist64[256];   // 2 KB
    __shared__ int S_B[2];
    __shared__ unsigned S_T[2];
    __shared__ int S_cnt, S_ecnt;
    __shared__ float S_conf;
    __shared__ unsigned S_mbits;

    if (t == 0) { S_cnt = 0; S_ecnt = 0; }
    // conf = min(0.25, max score); also keep max bits for find_bin start hint
    if (t < 64) {
        unsigned m = 0;
        for (int i = t; i < NGRP; i += 64) {
            unsigned v = wmaxg[b * NGRP + i];
            if (v > m) m = v;
        }
        for (int off = 32; off > 0; off >>= 1) {
            unsigned o = (unsigned)__shfl_down((int)m, off, 64);
            if (o > m) m = o;
        }
        if (t == 0) { S_conf = fminf(0.25f, __uint_as_float(m)); S_mbits = m; }
    }
    for (int i = t; i < 2048; i += 1024) { histA[i] = 0; histB[i] = 0; }
    __syncthreads();
    float conf = S_conf;
    // key build + pass-A histogram in ONE sweep
    const float4* sc4 = (const float4*)(scores + (size_t)b * NN);
    for (int n = t; n < NN / 4; n += 1024) {
        float4 v = sc4[n];
        unsigned k0 = (v.x >= conf) ? __float_as_uint(v.x) : 0u;
        unsigned k1 = (v.y >= conf) ? __float_as_uint(v.y) : 0u;
        unsigned k2 = (v.z >= conf) ? __float_as_uint(v.z) : 0u;
        unsigned k3 = (v.w >= conf) ? __float_as_uint(v.w) : 0u;
        skey[n * 4 + 0] = k0; atomicAdd(&histA[k0 >> 21], 1u);
        skey[n * 4 + 1] = k1; atomicAdd(&histA[k1 >> 21], 1u);
        skey[n * 4 + 2] = k2; atomicAdd(&histA[k2 >> 21], 1u);
        skey[n * 4 + 3] = k3; atomicAdd(&histA[k3 >> 21], 1u);
    }
    __syncthreads();
    if (t < 64) {
        int cs = (int)((S_mbits >> 21) >> 6); if (cs > 31) cs = 31;
        find_bin(histA, cs, 512u, t, &S_B[0], &S_T[0]);
    }
    __syncthreads();
    int B1 = S_B[0]; unsigned R1 = S_T[0];
    // pass B: bits[20:10] within top11==B1
    for (int n = t; n < NN; n += 1024) {
        unsigned k = skey[n];
        if ((int)(k >> 21) == B1) atomicAdd(&histB[(k >> 10) & 0x7FFu], 1u);
    }
    __syncthreads();
    if (t < 64) find_bin(histB, 31, R1, t, &S_B[1], &S_T[1]);
    __syncthreads();
    unsigned P = ((unsigned)B1 << 11) | (unsigned)S_B[1];
    unsigned R2 = S_T[1];
    // compact definite winners (top-22 > P), collect boundary bin (top-22 == P) as full keys
    for (int n = t; n < NN; n += 1024) {
        unsigned k = skey[n];
        if ((k >> 10) > P) {
            int pos = atomicAdd(&S_cnt, 1);
            list[pos] = ((unsigned long long)k << 32) | (unsigned long long)(unsigned)(~(unsigned)n);
        }
        if (P != 0u && (k >> 10) == P) {
            int ep = atomicAdd(&S_ecnt, 1);
            if (ep < 256) elist64[ep] = ((unsigned long long)k << 32) | (unsigned long long)(unsigned)(~(unsigned)n);
        }
    }
    __syncthreads();
    // boundary: take the top-R2 of the 22-bit-tied entries by full (key, ~idx) order
    int ecnt = S_ecnt; if (ecnt > 256) ecnt = 256;
    if (t < ecnt) {
        unsigned long long my = elist64[t];
        int r = 0;
        for (int j = 0; j < ecnt; j++) r += (elist64[j] > my) ? 1 : 0;
        if (r < (int)R2) {
            int pos = atomicAdd(&S_cnt, 1);
            list[pos] = my;
        }
    }
    __syncthreads();
    int nval = S_cnt;                              // == 512 unless fewer valid
    if (t == 0) nvalid[b] = nval;
    for (int i = nval + t; i < KPRE; i += 1024) list[i] = 0ull;
    __syncthreads();
    // exact rank via all-pairs compare -> sorted (descending top_k order)
    if (t < KPRE) {
        unsigned long long K0 = list[t];
        int r0 = 0;
        for (int j = 0; j < KPRE; j++) {
            unsigned long long L = list[j];        // wave-uniform broadcast read
            r0 += (L > K0) ? 1 : 0;
        }
        if (K0 != 0ull) sorted[r0] = K0; else sorted[t] = 0ull;
    }
    __syncthreads();
    // tiny gather: two float4 loads per row (decode already done in score_kernel)
    if (t < KPRE) {
        unsigned long long key = sorted[t];
        int valid = ((unsigned)(key >> 32)) != 0u;
        unsigned n = ~(unsigned)key;
        if (!valid) n = 0;
        size_t src = (size_t)b * NN + n;
        float4 rb = rawbox[src];
        float4 mi = minfo[src];
        float off = __fmul_rn(mi.z, 4096.0f);
        size_t o = (size_t)(b << 9) + t;
        boxraw[o] = rb;
        boxoff[o] = make_float4(rb.x + off, rb.y + off, rb.z + off, rb.w + off);
        meta[o] = make_float4(mi.x, mi.y, mi.z, valid ? 1.0f : 0.0f);
    }
}

// ---------------- Kernel C: IoU bitmatrix build (massively parallel) ----------------
__global__ __launch_bounds__(256) void iou_kernel(const float4* __restrict__ boxoff,
                                                  unsigned long long* __restrict__ ioug) {
    int b = blockIdx.y, t = threadIdx.x;
    int r = blockIdx.x * 64 + (t >> 2);
    int q = t & 3;
    __shared__ float4 sb[KPRE];
    for (int i = t; i < KPRE; i += 256) sb[i] = boxoff[(size_t)(b << 9) + i];
    __syncthreads();
    float4 bi = sb[r];
    float ai = __fmul_rn(bi.z - bi.x, bi.w - bi.y);
    unsigned long long w0 = 0ull, w1 = 0ull;
    int base = q * 128, rot = q * 33;
    for (int s = 0; s < 128; s++) {
        int jj = (s + rot) & 127;
        int jc = base + jj;
        float4 bj = sb[jc];
        float xx1 = fmaxf(bi.x, bj.x);
        float yy1 = fmaxf(bi.y, bj.y);
        float xx2 = fminf(bi.z, bj.z);
        float yy2 = fminf(bi.w, bj.w);
        float iw = fmaxf(xx2 - xx1, 0.0f);
        float ih = fmaxf(yy2 - yy1, 0.0f);
        float inter = __fmul_rn(iw, ih);
        float aj = __fmul_rn(bj.z - bj.x, bj.w - bj.y);
        float uni = (ai + aj) - inter;
        float iou = inter / (uni + 1e-9f);
        if (iou > 0.45f && jc < r) {
            if (jj < 64) w0 |= 1ull << jj;
            else         w1 |= 1ull << (jj - 64);
        }
    }
    size_t rowbase = ((size_t)(b << 9) + r) * 8 + q * 2;
    ioug[rowbase]     = w0;
    ioug[rowbase + 1] = w1;
}

// ---------------- Kernel D: sequential greedy scan + output ----------------
__global__ __launch_bounds__(64) void scan_kernel(const unsigned long long* __restrict__ ioug,
                                                  const int* __restrict__ nvalid,
                                                  const float4* __restrict__ boxraw,
                                                  const float4* __restrict__ meta,
                                                  float* __restrict__ out) {
    int b = blockIdx.x, t = threadIdx.x;
    __shared__ unsigned long long sl[528 * 8];      // 512 rows + 16 pad rows
    __shared__ unsigned long long skeep[8];

    const ulonglong2* src = (const ulonglong2*)(ioug + ((size_t)b << 12));
    ulonglong2* dst = (ulonglong2*)sl;
    for (int it = 0; it < 32; it++) dst[it * 64 + t] = src[it * 64 + t];
    sl[4096 + t] = 0ull;
    sl[4160 + t] = 0ull;
    __syncthreads();

    int w8 = t & 7;
    int nval = nvalid[b];
    unsigned long long keepW = 0ull;

#define STEP(ii, rwreg) { \
        bool hit = ((rwreg) & keepW) != 0ull; \
        unsigned long long bal = __ballot(hit); \
        bool kept = (bal == 0ull) && ((ii) < nval); \
        unsigned long long sb_ = (kept && (t == ((ii) >> 6))) ? (1ull << ((ii) & 63)) : 0ull; \
        keepW |= sb_; }

    unsigned long long A[8], Bf[8];
#pragma unroll
    for (int k = 0; k < 8; k++) A[k] = sl[(size_t)(0 + k) * 8 + w8];
#pragma unroll
    for (int k = 0; k < 8; k++) Bf[k] = sl[(size_t)(8 + k) * 8 + w8];
    for (int g = 0; g < 64; g += 2) {
        int base = g * 8;
#pragma unroll
        for (int k = 0; k < 8; k++) { STEP(base + k, A[k]); }
#pragma unroll
        for (int k = 0; k < 8; k++) A[k] = sl[(size_t)(base + 16 + k) * 8 + w8];
#pragma unroll
        for (int k = 0; k < 8; k++) { STEP(base + 8 + k, Bf[k]); }
#pragma unroll
        for (int k = 0; k < 8; k++) Bf[k] = sl[(size_t)(base + 24 + k) * 8 + w8];
    }
#undef STEP

    if (t < 8) skeep[t] = keepW;
    __syncthreads();

    float* dets = out + (size_t)b * (MAXOUT * 7);
    float* mask = out + (size_t)NB * MAXOUT * 7 + (size_t)b * MAXOUT;
    for (int m = t; m < MAXOUT * 7; m += 64) dets[m] = 0.0f;
    for (int m = t; m < MAXOUT; m += 64) mask[m] = 0.0f;

    for (int c = t; c < KPRE; c += 64) {
        int wq = c >> 6;
        unsigned long long kw = skeep[wq];
        int kept_c = (int)((kw >> (c & 63)) & 1ull);
        if (!kept_c) continue;
        int rank = 0;
        for (int w2 = 0; w2 < wq; w2++) rank += __popcll(skeep[w2]);
        rank += __popcll(kw & ((1ull << (c & 63)) - 1ull));
        if (rank < MAXOUT) {
            float4 rb = boxraw[(size_t)(b << 9) + c];
            float4 mt = meta[(size_t)(b << 9) + c];
            float* row = dets + rank * 7;
            row[0] = rb.x; row[1] = rb.y; row[2] = rb.z; row[3] = rb.w;
            row[4] = mt.x; row[5] = mt.y; row[6] = mt.z;
            mask[rank] = 1.0f;
        }
    }
}

extern "C" void kernel_launch(void* const* d_in, const int* in_sizes, int n_in,
                              void* d_out, int out_size, void* d_ws, size_t ws_size,
                              hipStream_t stream) {
    const float* pred = (const float*)d_in[0];
    float* out = (float*)d_out;

    char* ws = (char*)d_ws;
    unsigned* wmaxg = (unsigned*)ws;                                   // 32*263*4 = 33,664 -> pad 33,792
    float* scores = (float*)(ws + 33792);                              // 1,075,200 -> 1,108,992
    int* nvalid = (int*)(ws + 1108992);                                // 128 -> 1,109,120
    float4* boxoff = (float4*)(ws + 1109120);                          // 262,144 -> 1,371,264
    float4* boxraw = (float4*)(ws + 1371264);                          // 262,144 -> 1,633,408
    float4* meta   = (float4*)(ws + 1633408);                          // 262,144 -> 1,895,552
    unsigned long long* ioug = (unsigned long long*)(ws + 1895552);    // 1,048,576 -> 2,944,128
    float4* rawbox = (float4*)(ws + 2944128);                          // 4,300,800 -> 7,244,928
    float4* minfo  = (float4*)(ws + 7244928);                          // 4,300,800 -> 11,545,728

    dim3 gA(NGRP, NB);
    score_kernel<<<gA, 128, 0, stream>>>(pred, scores, wmaxg, rawbox, minfo);
    select_kernel<<<NB, 1024, 0, stream>>>(scores, wmaxg, rawbox, minfo, nvalid, boxoff, boxraw, meta);
    dim3 gI(8, NB);
    iou_kernel<<<gI, 256, 0, stream>>>(boxoff, ioug);
    scan_kernel<<<NB, 64, 0, stream>>>(ioug, nvalid, boxraw, meta, out);
}

// Round 11
// 203.284 us; speedup vs baseline: 1.1741x; 1.0004x over previous
//
#include <hip/hip_runtime.h>
#include <hip/hip_bf16.h>

#define NB 32
#define NN 8400
#define NC 80
#define KPRE 512
#define MAXOUT 100
#define NGRP 263   // score blocks per image; block = 2 waves x 16 rows
#define NWV 526    // wave-groups per image (per-wave maxima)

// ---------------- Kernel A: scores + per-anchor decode + per-WAVE max (no barrier) ----------------
// Each wave stages 16 rows (340 float4 = 5.4 KB); block LDS 10.9 KB -> 14 blocks/CU.
// 4 lanes share a row: q=lane&3 scans classes 20q..20q+19; two shfl_xor steps combine.
__global__ __launch_bounds__(128) void score_kernel(const float* __restrict__ pred,
                                                    float* __restrict__ scores,
                                                    unsigned* __restrict__ wmaxg,
                                                    float4* __restrict__ rawbox,
                                                    float4* __restrict__ minfo) {
    int b = blockIdx.y;
    int w = threadIdx.x >> 6, lane = threadIdx.x & 63;
    int g = blockIdx.x * 2 + w;                    // 16-row group in image (0..524 valid; 525 = pad)
    __shared__ float4 stg4[2][340];                // 16 rows x 85 floats per wave
    const float4* p4 = (const float4*)pred;
    size_t base4 = (size_t)b * 178500 + (size_t)g * 340;
    size_t img_end4 = ((size_t)b + 1) * 178500;
    for (int k = lane; k < 340; k += 64) {
        size_t e = base4 + k;
        if (e >= img_end4) e = img_end4 - 1;       // clamp tail (invalid groups discarded below)
        stg4[w][k] = p4[e];
    }
    // no cross-wave LDS sharing -> no barrier needed (compiler waits lgkmcnt within wave)
    int rl = lane >> 2, q = lane & 3;
    int row = g * 16 + rl;
    const float* r = (const float*)&stg4[w][0] + rl * 85;
    float cx = r[0], cy = r[1], bw = r[2], bh = r[3], obj = r[4];
    int c0 = 5 + q * 20;
    float cc = r[c0];
    int cp = q * 20;
    for (int c = 1; c < 20; c++) {
        float v = r[c0 + c];
        if (v > cc) { cc = v; cp = q * 20 + c; }   // strict >: first-max within quarter
    }
    // combine 4-lane group; tie -> lower class index
    {
        float cc1 = __shfl_xor(cc, 1, 64); int cp1 = __shfl_xor(cp, 1, 64);
        bool take = (cc1 > cc) || (cc1 == cc && cp1 < cp);
        cc = take ? cc1 : cc; cp = take ? cp1 : cp;
        float cc2 = __shfl_xor(cc, 2, 64); int cp2 = __shfl_xor(cp, 2, 64);
        take = (cc2 > cc) || (cc2 == cc && cp2 < cp);
        cc = take ? cc2 : cc; cp = take ? cp2 : cp;
    }
    float s = __fmul_rn(obj, cc);
    float hw = __fmul_rn(bw, 0.5f), hh = __fmul_rn(bh, 0.5f);
    float x1 = cx - hw, y1 = cy - hh, x2 = cx + hw, y2 = cy + hh;
    // redistribute: lane l<16 takes row l's result (lives in lane 4l), coalesced writes
    int srcl = (lane & 15) * 4;
    float v0 = __shfl(x1, srcl, 64);
    float v1 = __shfl(y1, srcl, 64);
    float v2 = __shfl(x2, srcl, 64);
    float v3 = __shfl(y2, srcl, 64);
    float v4 = __shfl(obj, srcl, 64);
    float v5 = __shfl(cc, srcl, 64);
    int   v6 = __shfl(cp, srcl, 64);
    float v7 = __shfl(s, srcl, 64);
    int wrow = g * 16 + (lane & 15);
    if (lane < 16 && wrow < NN) {
        size_t idx = (size_t)b * NN + wrow;
        scores[idx] = v7;
        rawbox[idx] = make_float4(v0, v1, v2, v3);
        minfo[idx]  = make_float4(v4, v5, (float)v6, v7);
    }
    // per-wave max (invalid rows -> 0); every wmaxg slot written -> no init needed
    if (row >= NN) s = 0.0f;
    unsigned bits = __float_as_uint(s);
    for (int o = 32; o > 0; o >>= 1) {
        unsigned other = (unsigned)__shfl_down((int)bits, o, 64);
        if (other > bits) bits = other;
    }
    if (lane == 0) wmaxg[b * NWV + g] = bits;
}

// ---- wave-0 helper: largest bin B with suffix(B) >= T over hist[0..(cstart+1)*64);
// R = T - suffix(B+1). Scans chunks downward starting at cstart.
__device__ __forceinline__ void find_bin(const unsigned* hist, int cstart, unsigned T, int lane,
                                         int* outB, unsigned* outR) {
    unsigned running = 0;
    for (int c = cstart; c >= 0; c--) {
        unsigned v = hist[c * 64 + lane];
        unsigned s = v;
        for (int off = 1; off < 64; off <<= 1) {
            unsigned u = (unsigned)__shfl_down((int)s, off, 64);
            if (lane + off < 64) s += u;
        }
        unsigned total0 = (unsigned)__shfl((int)s, 0, 64);
        if (total0 + running >= T) {
            unsigned long long mask = __ballot(s + running >= T);
            int m = 63 - __clzll(mask);
            unsigned sm = (unsigned)__shfl((int)s, m, 64);
            unsigned vm = (unsigned)__shfl((int)v, m, 64);
            if (lane == 0) { *outB = c * 64 + m; *outR = T - (sm + running - vm); }
            return;
        }
        running += total0;
    }
    if (lane == 0) { *outB = 0; *outR = T; }   // fewer than T valid keys in range
}

// ---------------- Kernel B: top-512 radix select, register-resident keys ----------------
// Thread t owns anchors 8t..8t+7 (2x float4); t<52 additionally owns 8192+4t..+3 (1x float4).
// Pass A (bits[31:21]) histogrammed during the build sweep; pass B bits[20:10]; boundary bin
// resolved exactly by all-pairs rank over full (key,~idx).
__global__ __launch_bounds__(1024) void select_kernel(const float* __restrict__ scores,
                                                      const unsigned* __restrict__ wmaxg,
                                                      const float4* __restrict__ rawbox,
                                                      const float4* __restrict__ minfo,
                                                      int* __restrict__ nvalid,
                                                      float4* __restrict__ boxoff,
                                                      float4* __restrict__ boxraw,
                                                      float4* __restrict__ meta) {
    int b = blockIdx.x, t = threadIdx.x;
    __shared__ unsigned histA[2048];              // 8 KB
    __shared__ unsigned histB[2048];              // 8 KB
    __shared__ unsigned long long list[KPRE];     // 4 KB
    __shared__ unsigned long long sorted[KPRE];   // 4 KB
    __shared__ unsigned long long elist64[256];   // 2 KB
    __shared__ int S_B[2];
    __shared__ unsigned S_T[2];
    __shared__ int S_cnt, S_ecnt;
    __shared__ float S_conf;
    __shared__ unsigned S_mbits;

    if (t == 0) { S_cnt = 0; S_ecnt = 0; }
    // conf = min(0.25, max score) from per-wave maxima; keep bits for find_bin start hint
    if (t < 64) {
        unsigned m = 0;
        for (int i = t; i < NWV; i += 64) {
            unsigned v = wmaxg[b * NWV + i];
            if (v > m) m = v;
        }
        for (int off = 32; off > 0; off >>= 1) {
            unsigned o = (unsigned)__shfl_down((int)m, off, 64);
            if (o > m) m = o;
        }
        if (t == 0) { S_conf = fminf(0.25f, __uint_as_float(m)); S_mbits = m; }
    }
    for (int i = t; i < 2048; i += 1024) { histA[i] = 0; histB[i] = 0; }
    __syncthreads();
    float conf = S_conf;
    // key build (registers) + pass-A histogram in ONE sweep
    const float4* sc4 = (const float4*)(scores + (size_t)b * NN);
    unsigned ka[8];
    unsigned kb[4] = {0u, 0u, 0u, 0u};
    {
        float4 u0 = sc4[2 * t], u1 = sc4[2 * t + 1];
        ka[0] = (u0.x >= conf) ? __float_as_uint(u0.x) : 0u;
        ka[1] = (u0.y >= conf) ? __float_as_uint(u0.y) : 0u;
        ka[2] = (u0.z >= conf) ? __float_as_uint(u0.z) : 0u;
        ka[3] = (u0.w >= conf) ? __float_as_uint(u0.w) : 0u;
        ka[4] = (u1.x >= conf) ? __float_as_uint(u1.x) : 0u;
        ka[5] = (u1.y >= conf) ? __float_as_uint(u1.y) : 0u;
        ka[6] = (u1.z >= conf) ? __float_as_uint(u1.z) : 0u;
        ka[7] = (u1.w >= conf) ? __float_as_uint(u1.w) : 0u;
        if (t < 52) {                              // tail anchors 8192..8399
            float4 u2 = sc4[2048 + t];
            kb[0] = (u2.x >= conf) ? __float_as_uint(u2.x) : 0u;
            kb[1] = (u2.y >= conf) ? __float_as_uint(u2.y) : 0u;
            kb[2] = (u2.z >= conf) ? __float_as_uint(u2.z) : 0u;
            kb[3] = (u2.w >= conf) ? __float_as_uint(u2.w) : 0u;
        }
#pragma unroll
        for (int j = 0; j < 8; j++) atomicAdd(&histA[ka[j] >> 21], 1u);
        if (t < 52) {
#pragma unroll
            for (int j = 0; j < 4; j++) atomicAdd(&histA[kb[j] >> 21], 1u);
        }
    }
    __syncthreads();
    if (t < 64) {
        int cs = (int)(S_mbits >> 27); if (cs > 31) cs = 31;
        find_bin(histA, cs, 512u, t, &S_B[0], &S_T[0]);
    }
    __syncthreads();
    int B1 = S_B[0]; unsigned R1 = S_T[0];
    // pass B: bits[20:10] within top11==B1 (register sweep)
#pragma unroll
    for (int j = 0; j < 8; j++) {
        unsigned k = ka[j];
        if ((int)(k >> 21) == B1) atomicAdd(&histB[(k >> 10) & 0x7FFu], 1u);
    }
    if (t < 52) {
#pragma unroll
        for (int j = 0; j < 4; j++) {
            unsigned k = kb[j];
            if ((int)(k >> 21) == B1) atomicAdd(&histB[(k >> 10) & 0x7FFu], 1u);
        }
    }
    __syncthreads();
    if (t < 64) find_bin(histB, 31, R1, t, &S_B[1], &S_T[1]);
    __syncthreads();
    unsigned P = ((unsigned)B1 << 11) | (unsigned)S_B[1];
    unsigned R2 = S_T[1];
    // compact definite winners (top-22 > P); collect boundary bin (top-22 == P) as full keys
#pragma unroll
    for (int j = 0; j < 8; j++) {
        unsigned k = ka[j];
        unsigned n = 8u * (unsigned)t + (unsigned)j;
        if ((k >> 10) > P) {
            int pos = atomicAdd(&S_cnt, 1);
            list[pos] = ((unsigned long long)k << 32) | (unsigned long long)(unsigned)(~n);
        } else if (P != 0u && (k >> 10) == P) {
            int ep = atomicAdd(&S_ecnt, 1);
            if (ep < 256) elist64[ep] = ((unsigned long long)k << 32) | (unsigned long long)(unsigned)(~n);
        }
    }
    if (t < 52) {
#pragma unroll
        for (int j = 0; j < 4; j++) {
            unsigned k = kb[j];
            unsigned n = 8192u + 4u * (unsigned)t + (unsigned)j;
            if ((k >> 10) > P) {
                int pos = atomicAdd(&S_cnt, 1);
                list[pos] = ((unsigned long long)k << 32) | (unsigned long long)(unsigned)(~n);
            } else if (P != 0u && (k >> 10) == P) {
                int ep = atomicAdd(&S_ecnt, 1);
                if (ep < 256) elist64[ep] = ((unsigned long long)k << 32) | (unsigned long long)(unsigned)(~n);
            }
        }
    }
    __syncthreads();
    // boundary: take the top-R2 of the 22-bit-tied entries by full (key, ~idx) order
    int ecnt = S_ecnt; if (ecnt > 256) ecnt = 256;
    if (t < ecnt) {
        unsigned long long my = elist64[t];
        int r = 0;
        for (int j = 0; j < ecnt; j++) r += (elist64[j] > my) ? 1 : 0;
        if (r < (int)R2) {
            int pos = atomicAdd(&S_cnt, 1);
            list[pos] = my;
        }
    }
    __syncthreads();
    int nval = S_cnt;                              // == 512 unless fewer valid
    if (t == 0) nvalid[b] = nval;
    for (int i = nval + t; i < KPRE; i += 1024) list[i] = 0ull;
    __syncthreads();
    // exact rank via all-pairs compare -> sorted (descending top_k order)
    if (t < KPRE) {
        unsigned long long K0 = list[t];
        int r0 = 0;
        for (int j = 0; j < KPRE; j++) {
            unsigned long long L = list[j];        // wave-uniform broadcast read
            r0 += (L > K0) ? 1 : 0;
        }
        if (K0 != 0ull) sorted[r0] = K0; else sorted[t] = 0ull;
    }
    __syncthreads();
    // tiny gather: two float4 loads per row (decode already done in score_kernel)
    if (t < KPRE) {
        unsigned long long key = sorted[t];
        int valid = ((unsigned)(key >> 32)) != 0u;
        unsigned n = ~(unsigned)key;
        if (!valid) n = 0;
        size_t src = (size_t)b * NN + n;
        float4 rb = rawbox[src];
        float4 mi = minfo[src];
        float off = __fmul_rn(mi.z, 4096.0f);
        size_t o = (size_t)(b << 9) + t;
        boxraw[o] = rb;
        boxoff[o] = make_float4(rb.x + off, rb.y + off, rb.z + off, rb.w + off);
        meta[o] = make_float4(mi.x, mi.y, mi.z, valid ? 1.0f : 0.0f);
    }
}

// ---------------- Kernel C: IoU bitmatrix build (massively parallel) ----------------
__global__ __launch_bounds__(256) void iou_kernel(const float4* __restrict__ boxoff,
                                                  unsigned long long* __restrict__ ioug) {
    int b = blockIdx.y, t = threadIdx.x;
    int r = blockIdx.x * 64 + (t >> 2);
    int q = t & 3;
    __shared__ float4 sb[KPRE];
    for (int i = t; i < KPRE; i += 256) sb[i] = boxoff[(size_t)(b << 9) + i];
    __syncthreads();
    float4 bi = sb[r];
    float ai = __fmul_rn(bi.z - bi.x, bi.w - bi.y);
    unsigned long long w0 = 0ull, w1 = 0ull;
    int base = q * 128, rot = q * 33;
    for (int s = 0; s < 128; s++) {
        int jj = (s + rot) & 127;
        int jc = base + jj;
        float4 bj = sb[jc];
        float xx1 = fmaxf(bi.x, bj.x);
        float yy1 = fmaxf(bi.y, bj.y);
        float xx2 = fminf(bi.z, bj.z);
        float yy2 = fminf(bi.w, bj.w);
        float iw = fmaxf(xx2 - xx1, 0.0f);
        float ih = fmaxf(yy2 - yy1, 0.0f);
        float inter = __fmul_rn(iw, ih);
        float aj = __fmul_rn(bj.z - bj.x, bj.w - bj.y);
        float uni = (ai + aj) - inter;
        float iou = inter / (uni + 1e-9f);
        if (iou > 0.45f && jc < r) {
            if (jj < 64) w0 |= 1ull << jj;
            else         w1 |= 1ull << (jj - 64);
        }
    }
    size_t rowbase = ((size_t)(b << 9) + r) * 8 + q * 2;
    ioug[rowbase]     = w0;
    ioug[rowbase + 1] = w1;
}

// ---------------- Kernel D: sequential greedy scan + output ----------------
__global__ __launch_bounds__(64) void scan_kernel(const unsigned long long* __restrict__ ioug,
                                                  const int* __restrict__ nvalid,
                                                  const float4* __restrict__ boxraw,
                                                  const float4* __restrict__ meta,
                                                  float* __restrict__ out) {
    int b = blockIdx.x, t = threadIdx.x;
    __shared__ unsigned long long sl[528 * 8];      // 512 rows + 16 pad rows
    __shared__ unsigned long long skeep[8];

    const ulonglong2* src = (const ulonglong2*)(ioug + ((size_t)b << 12));
    ulonglong2* dst = (ulonglong2*)sl;
    for (int it = 0; it < 32; it++) dst[it * 64 + t] = src[it * 64 + t];
    sl[4096 + t] = 0ull;
    sl[4160 + t] = 0ull;
    __syncthreads();

    int w8 = t & 7;
    int nval = nvalid[b];
    unsigned long long keepW = 0ull;

#define STEP(ii, rwreg) { \
        bool hit = ((rwreg) & keepW) != 0ull; \
        unsigned long long bal = __ballot(hit); \
        bool kept = (bal == 0ull) && ((ii) < nval); \
        unsigned long long sb_ = (kept && (t == ((ii) >> 6))) ? (1ull << ((ii) & 63)) : 0ull; \
        keepW |= sb_; }

    unsigned long long A[8], Bf[8];
#pragma unroll
    for (int k = 0; k < 8; k++) A[k] = sl[(size_t)(0 + k) * 8 + w8];
#pragma unroll
    for (int k = 0; k < 8; k++) Bf[k] = sl[(size_t)(8 + k) * 8 + w8];
    for (int g = 0; g < 64; g += 2) {
        int base = g * 8;
#pragma unroll
        for (int k = 0; k < 8; k++) { STEP(base + k, A[k]); }
#pragma unroll
        for (int k = 0; k < 8; k++) A[k] = sl[(size_t)(base + 16 + k) * 8 + w8];
#pragma unroll
        for (int k = 0; k < 8; k++) { STEP(base + 8 + k, Bf[k]); }
#pragma unroll
        for (int k = 0; k < 8; k++) Bf[k] = sl[(size_t)(base + 24 + k) * 8 + w8];
    }
#undef STEP

    if (t < 8) skeep[t] = keepW;
    __syncthreads();

    float* dets = out + (size_t)b * (MAXOUT * 7);
    float* mask = out + (size_t)NB * MAXOUT * 7 + (size_t)b * MAXOUT;
    for (int m = t; m < MAXOUT * 7; m += 64) dets[m] = 0.0f;
    for (int m = t; m < MAXOUT; m += 64) mask[m] = 0.0f;

    for (int c = t; c < KPRE; c += 64) {
        int wq = c >> 6;
        unsigned long long kw = skeep[wq];
        int kept_c = (int)((kw >> (c & 63)) & 1ull);
        if (!kept_c) continue;
        int rank = 0;
        for (int w2 = 0; w2 < wq; w2++) rank += __popcll(skeep[w2]);
        rank += __popcll(kw & ((1ull << (c & 63)) - 1ull));
        if (rank < MAXOUT) {
            float4 rb = boxraw[(size_t)(b << 9) + c];
            float4 mt = meta[(size_t)(b << 9) + c];
            float* row = dets + rank * 7;
            row[0] = rb.x; row[1] = rb.y; row[2] = rb.z; row[3] = rb.w;
            row[4] = mt.x; row[5] = mt.y; row[6] = mt.z;
            mask[rank] = 1.0f;
        }
    }
}

extern "C" void kernel_launch(void* const* d_in, const int* in_sizes, int n_in,
                              void* d_out, int out_size, void* d_ws, size_t ws_size,
                              hipStream_t stream) {
    const float* pred = (const float*)d_in[0];
    float* out = (float*)d_out;

    char* ws = (char*)d_ws;
    unsigned* wmaxg = (unsigned*)ws;                                   // 32*526*4 = 67,328 -> pad 67,584
    float* scores = (float*)(ws + 67584);                              // 1,075,200 -> 1,142,784
    int* nvalid = (int*)(ws + 1142784);                                // 128 -> 1,142,912
    float4* boxoff = (float4*)(ws + 1142912);                          // 262,144 -> 1,405,056
    float4* boxraw = (float4*)(ws + 1405056);                          // 262,144 -> 1,667,200
    float4* meta   = (float4*)(ws + 1667200);                          // 262,144 -> 1,929,344
    unsigned long long* ioug = (unsigned long long*)(ws + 1929344);    // 1,048,576 -> 2,977,920
    float4* rawbox = (float4*)(ws + 2977920);                          // 4,300,800 -> 7,278,720
    float4* minfo  = (float4*)(ws + 7278720);                          // 4,300,800 -> 11,579,520

    dim3 gA(NGRP, NB);
    score_kernel<<<gA, 128, 0, stream>>>(pred, scores, wmaxg, rawbox, minfo);
    select_kernel<<<NB, 1024, 0, stream>>>(scores, wmaxg, rawbox, minfo, nvalid, boxoff, boxraw, meta);
    dim3 gI(8, NB);
    iou_kernel<<<gI, 256, 0, stream>>>(boxoff, ioug);
    scan_kernel<<<NB, 64, 0, stream>>>(ioug, nvalid, boxraw, meta, out);
}